// Round 1
// baseline (114.125 us; speedup 1.0000x reference)
//
#include <hip/hip_runtime.h>
#include <math.h>

#define BATCH 2
#define NPTS (64*64*64)       // 262144 points per batch
#define CIN 32
#define COUT 32
#define NF 64
#define NFEAT 20
#define TWO_PI_F 6.283185307179586f

// ws layout (floats)
#define WS_M 0                          // BATCH*NFEAT*CIN   = 1280
#define WS_G (BATCH*NFEAT*CIN)          // BATCH*NF*2*COUT   = 8192
#define WS_V (WS_G + BATCH*NF*2*COUT)   // BATCH*NFEAT*COUT  = 1280

// monomial exponent tables (degree <= 3 in 3 vars), order must match monomials()
__device__ const int   d_EX0[NFEAT]  = {0,1,0,0,2,1,1,0,0,0,3,2,2,1,1,1,0,0,0,0};
__device__ const int   d_EX1[NFEAT]  = {0,0,1,0,0,1,0,2,1,0,0,1,0,2,1,0,3,2,1,0};
__device__ const int   d_EX2[NFEAT]  = {0,0,0,1,0,0,1,0,1,2,0,0,1,0,1,2,0,1,2,3};
__device__ const float d_MULT[NFEAT] = {1,1,1,1,1,2,2,1,2,1,1,3,3,3,6,3,1,3,3,1};

__device__ __forceinline__ void monomials(float x0, float x1, float x2, float* m) {
    m[0] = 1.f;  m[1] = x0;   m[2] = x1;   m[3] = x2;
    m[4] = x0*x0; m[5] = x0*x1; m[6] = x0*x2; m[7] = x1*x1; m[8] = x1*x2; m[9] = x2*x2;
    m[10] = m[4]*x0; m[11] = m[4]*x1; m[12] = m[4]*x2; m[13] = m[7]*x0; m[14] = m[5]*x2;
    m[15] = m[9]*x0; m[16] = m[7]*x1; m[17] = m[7]*x2; m[18] = m[9]*x1; m[19] = m[9]*x2;
}

// K1: M[b][feat][i] = sum_p mono_feat(x_p) * h[p][i]
__global__ __launch_bounds__(256) void k1_moments(const float* __restrict__ h,
                                                  const float* __restrict__ x,
                                                  float* __restrict__ mws) {
    const int blk = blockIdx.x;            // 1024 blocks: 512 per batch
    const int b = blk >> 9;
    const int blkin = blk & 511;
    const int t = threadIdx.x;
    const int i = t & 31;                  // channel
    const int psub = t >> 5;               // 0..7
    const int PPB = NPTS / 512;            // 512 points per block

    size_t pbase = (size_t)b * NPTS + (size_t)blkin * PPB;

    float acc[NFEAT];
#pragma unroll
    for (int q = 0; q < NFEAT; ++q) acc[q] = 0.f;

#pragma unroll 2
    for (int k = 0; k < PPB / 8; ++k) {
        size_t p = pbase + (size_t)psub + 8u * (size_t)k;
        float x0 = x[p * 3 + 0];
        float x1 = x[p * 3 + 1];
        float x2 = x[p * 3 + 2];
        float hv = h[p * 32 + i];
        float m[NFEAT];
        monomials(x0, x1, x2, m);
#pragma unroll
        for (int q = 0; q < NFEAT; ++q) acc[q] = fmaf(m[q], hv, acc[q]);
    }

    __shared__ float tile[NFEAT * CIN];
    for (int idx = t; idx < NFEAT * CIN; idx += 256) tile[idx] = 0.f;
    __syncthreads();
#pragma unroll
    for (int q = 0; q < NFEAT; ++q) atomicAdd(&tile[q * CIN + i], acc[q]);
    __syncthreads();
    for (int idx = t; idx < NFEAT * CIN; idx += 256)
        atomicAdd(&mws[b * NFEAT * CIN + idx], tile[idx]);
}

// K2a: per (b,f): H_re/H_im from M, then G = H @ kernel (complex)
__global__ __launch_bounds__(64) void k2a_HG(const float* __restrict__ mws,
                                             const float* __restrict__ modes,
                                             const float* __restrict__ kre,
                                             const float* __restrict__ kim,
                                             float* __restrict__ gws) {
    const int bf = blockIdx.x;             // 128 = BATCH*NF
    const int b = bf >> 6, f = bf & 63;
    const int t = threadIdx.x;
    const int half = t >> 5;               // 0: re, 1: im
    const int lane = t & 31;

    const float u0 = TWO_PI_F * modes[f * 3 + 0];
    const float u1 = TWO_PI_F * modes[f * 3 + 1];
    const float u2 = TWO_PI_F * modes[f * 3 + 2];

    __shared__ float sH[2][32];

    const float* Mb = mws + b * NFEAT * CIN;
    float hv = 0.f;
#pragma unroll
    for (int fi = 0; fi < NFEAT; ++fi) {
        const int e0 = d_EX0[fi], e1 = d_EX1[fi], e2 = d_EX2[fi];
        const int deg = e0 + e1 + e2;
        float up = d_MULT[fi];
#pragma unroll
        for (int r = 0; r < 3; ++r) { if (r < e0) up *= u0; }
#pragma unroll
        for (int r = 0; r < 3; ++r) { if (r < e1) up *= u1; }
#pragma unroll
        for (int r = 0; r < 3; ++r) { if (r < e2) up *= u2; }
        float cc = (deg == 0) ? 1.f : ((deg == 2) ? -0.5f * up : 0.f);
        float cs = (deg == 1) ? up : ((deg == 3) ? -(1.f / 6.f) * up : 0.f);
        // H_re = sum ccos*M ; H_im = -sum csin*M
        float coef = (half == 0) ? cc : -cs;
        hv = fmaf(coef, Mb[fi * CIN + lane], hv);
    }
    sH[half][lane] = hv;
    __syncthreads();

    float go = 0.f;
#pragma unroll 8
    for (int i2 = 0; i2 < CIN; ++i2) {
        float a = kre[((size_t)f * CIN + i2) * COUT + lane];
        float c = kim[((size_t)f * CIN + i2) * COUT + lane];
        float hre = sH[0][i2], him = sH[1][i2];
        go += (half == 0) ? (hre * a - him * c) : (hre * c + him * a);
    }
    gws[(((size_t)b * NF + f) * 2 + half) * COUT + lane] = go;
}

// K2b: V[b][feat][o] = sum_f ccos*Gre - csin*Gim ; fold in fc_w/fc_b
__global__ __launch_bounds__(640) void k2b_V(const float* __restrict__ gws,
                                             const float* __restrict__ modes,
                                             const float* __restrict__ fcw,
                                             const float* __restrict__ fcb,
                                             float* __restrict__ vws) {
    const int b = blockIdx.x;              // 2
    const int t = threadIdx.x;             // 640 = 20*32
    const int fi = t >> 5;
    const int o = t & 31;

    const int e0 = d_EX0[fi], e1 = d_EX1[fi], e2 = d_EX2[fi];
    const int deg = e0 + e1 + e2;
    const float mult = d_MULT[fi];

    float acc = 0.f;
    for (int f = 0; f < NF; ++f) {
        float u0 = TWO_PI_F * modes[f * 3 + 0];
        float u1 = TWO_PI_F * modes[f * 3 + 1];
        float u2 = TWO_PI_F * modes[f * 3 + 2];
        float up = mult;
        for (int r = 0; r < e0; ++r) up *= u0;
        for (int r = 0; r < e1; ++r) up *= u1;
        for (int r = 0; r < e2; ++r) up *= u2;
        float cc = (deg == 0) ? 1.f : ((deg == 2) ? -0.5f * up : 0.f);
        float cs = (deg == 1) ? up : ((deg == 3) ? -(1.f / 6.f) * up : 0.f);
        float gre = gws[(((size_t)b * NF + f) * 2 + 0) * COUT + o];
        float gim = gws[(((size_t)b * NF + f) * 2 + 1) * COUT + o];
        acc += cc * gre - cs * gim;
    }
    if (fi == 0) acc += fcb[o];
    else if (deg == 1) acc += fcw[(fi - 1) * COUT + o];
    vws[(b * NFEAT + fi) * COUT + o] = acc;
}

// K3: out[p][o] = gelu( sum_feat mono(x_p) * V[b][feat][o] )
__global__ __launch_bounds__(256) void k3_out(const float* __restrict__ x,
                                              const float* __restrict__ vws,
                                              float* __restrict__ out) {
    const int blk = blockIdx.x;            // 1024: 512 per batch
    const int b = blk >> 9;
    const int blkin = blk & 511;
    const int t = threadIdx.x;
    const int o = t & 31;
    const int psub = t >> 5;
    const int PPB = NPTS / 512;

    float v[NFEAT];
#pragma unroll
    for (int q = 0; q < NFEAT; ++q) v[q] = vws[(b * NFEAT + q) * COUT + o];

    size_t pbase = (size_t)b * NPTS + (size_t)blkin * PPB;

#pragma unroll 2
    for (int k = 0; k < PPB / 8; ++k) {
        size_t p = pbase + (size_t)psub + 8u * (size_t)k;
        float x0 = x[p * 3 + 0];
        float x1 = x[p * 3 + 1];
        float x2 = x[p * 3 + 2];
        float m[NFEAT];
        monomials(x0, x1, x2, m);
        float y = 0.f;
#pragma unroll
        for (int q = 0; q < NFEAT; ++q) y = fmaf(m[q], v[q], y);
        // tanh-approx gelu (matches jax.nn.gelu approximate=True)
        float tt = 0.7978845608028654f * (y + 0.044715f * y * y * y);
        float e = __expf(2.f * tt);
        float r = y * (1.f - 1.f / (e + 1.f));   // y*(1+tanh(tt))/2
        out[p * 32 + o] = r;
    }
}

extern "C" void kernel_launch(void* const* d_in, const int* in_sizes, int n_in,
                              void* d_out, int out_size, void* d_ws, size_t ws_size,
                              hipStream_t stream) {
    const float* h     = (const float*)d_in[0];
    const float* x     = (const float*)d_in[1];
    const float* modes = (const float*)d_in[2];
    const float* kre   = (const float*)d_in[3];
    const float* kim   = (const float*)d_in[4];
    const float* fcw   = (const float*)d_in[5];
    const float* fcb   = (const float*)d_in[6];
    float* out = (float*)d_out;
    float* ws  = (float*)d_ws;

    // zero the moment accumulator region (atomically accumulated by K1)
    hipMemsetAsync(ws + WS_M, 0, BATCH * NFEAT * CIN * sizeof(float), stream);

    k1_moments<<<1024, 256, 0, stream>>>(h, x, ws + WS_M);
    k2a_HG<<<BATCH * NF, 64, 0, stream>>>(ws + WS_M, modes, kre, kim, ws + WS_G);
    k2b_V<<<BATCH, NFEAT * COUT, 0, stream>>>(ws + WS_G, modes, fcw, fcb, ws + WS_V);
    k3_out<<<1024, 256, 0, stream>>>(x, ws + WS_V, out);
}

// Round 2
// 86.800 us; speedup vs baseline: 1.3148x; 1.3148x over previous
//
#include <hip/hip_runtime.h>
#include <math.h>

#define BATCH 2
#define NPTS (64*64*64)       // 262144 points per batch
#define CIN 32
#define COUT 32
#define NF 64
#define NFEAT 20
#define TWO_PI_F 6.283185307179586f

// ws layout (floats)
#define WS_M 0                          // BATCH*NFEAT*CIN   = 1280
#define WS_G (BATCH*NFEAT*CIN)          // BATCH*NF*2*COUT   = 8192
#define WS_V (WS_G + BATCH*NF*2*COUT)   // BATCH*NFEAT*COUT  = 1280

// monomial exponent tables (degree <= 3 in 3 vars), order must match monomials()
__device__ const int   d_EX0[NFEAT]  = {0,1,0,0,2,1,1,0,0,0,3,2,2,1,1,1,0,0,0,0};
__device__ const int   d_EX1[NFEAT]  = {0,0,1,0,0,1,0,2,1,0,0,1,0,2,1,0,3,2,1,0};
__device__ const int   d_EX2[NFEAT]  = {0,0,0,1,0,0,1,0,1,2,0,0,1,0,1,2,0,1,2,3};
__device__ const float d_MULT[NFEAT] = {1,1,1,1,1,2,2,1,2,1,1,3,3,3,6,3,1,3,3,1};

__device__ __forceinline__ void monomials(float x0, float x1, float x2, float* m) {
    m[0] = 1.f;  m[1] = x0;   m[2] = x1;   m[3] = x2;
    m[4] = x0*x0; m[5] = x0*x1; m[6] = x0*x2; m[7] = x1*x1; m[8] = x1*x2; m[9] = x2*x2;
    m[10] = m[4]*x0; m[11] = m[4]*x1; m[12] = m[4]*x2; m[13] = m[7]*x0; m[14] = m[5]*x2;
    m[15] = m[9]*x0; m[16] = m[7]*x1; m[17] = m[7]*x2; m[18] = m[9]*x1; m[19] = m[9]*x2;
}

__device__ __forceinline__ float gelu_f(float y) {
    float tt = 0.7978845608028654f * (y + 0.044715f * y * y * y);
    float e = __expf(2.f * tt);
    return y * (1.f - 1.f / (e + 1.f));   // y*(1+tanh(tt))/2
}

// K1: M[b][feat][i] = sum_p mono_feat(x_p) * h[p][i]
// 8 threads per point, each owns a 4-channel quad (float4 h loads).
__global__ __launch_bounds__(256) void k1_moments(const float* __restrict__ h,
                                                  const float* __restrict__ x,
                                                  float* __restrict__ mws) {
    const int blk = blockIdx.x;            // 1024 blocks: 512 per batch
    const int b = blk >> 9;
    const int blkin = blk & 511;
    const int t = threadIdx.x;
    const int q = t & 7;                   // channel quad 0..7
    const int i4 = q << 2;                 // channel base
    const int psub = t >> 3;               // 0..31 point slot
    const int PPB = NPTS / 512;            // 512 points per block
    const int NIT = PPB / 32;              // 16 iterations, 32 points each

    const size_t pbase = (size_t)b * NPTS + (size_t)blkin * PPB;

    float4 acc[NFEAT];
#pragma unroll
    for (int f = 0; f < NFEAT; ++f) acc[f] = make_float4(0.f, 0.f, 0.f, 0.f);

#pragma unroll 2
    for (int k = 0; k < NIT; ++k) {
        size_t p = pbase + (size_t)psub + 32u * (size_t)k;
        float x0 = x[p * 3 + 0];
        float x1 = x[p * 3 + 1];
        float x2 = x[p * 3 + 2];
        float4 hv = *reinterpret_cast<const float4*>(&h[p * 32 + i4]);
        float m[NFEAT];
        monomials(x0, x1, x2, m);
#pragma unroll
        for (int f = 0; f < NFEAT; ++f) {
            acc[f].x = fmaf(m[f], hv.x, acc[f].x);
            acc[f].y = fmaf(m[f], hv.y, acc[f].y);
            acc[f].z = fmaf(m[f], hv.z, acc[f].z);
            acc[f].w = fmaf(m[f], hv.w, acc[f].w);
        }
    }

    // reduce over the 8 lanes (stride 8) sharing this channel quad within the wave
#pragma unroll
    for (int off = 8; off <= 32; off <<= 1) {
#pragma unroll
        for (int f = 0; f < NFEAT; ++f) {
            acc[f].x += __shfl_down(acc[f].x, off, 64);
            acc[f].y += __shfl_down(acc[f].y, off, 64);
            acc[f].z += __shfl_down(acc[f].z, off, 64);
            acc[f].w += __shfl_down(acc[f].w, off, 64);
        }
    }

    // per-wave partials -> LDS (non-atomic), then one global atomic per entry
    __shared__ float tileP[4][NFEAT * CIN];   // 4 waves
    const int w = t >> 6;
    const int lane = t & 63;
    if (lane < 8) {
#pragma unroll
        for (int f = 0; f < NFEAT; ++f) {
            tileP[w][f * CIN + i4 + 0] = acc[f].x;
            tileP[w][f * CIN + i4 + 1] = acc[f].y;
            tileP[w][f * CIN + i4 + 2] = acc[f].z;
            tileP[w][f * CIN + i4 + 3] = acc[f].w;
        }
    }
    __syncthreads();
    for (int idx = t; idx < NFEAT * CIN; idx += 256) {
        float s = tileP[0][idx] + tileP[1][idx] + tileP[2][idx] + tileP[3][idx];
        atomicAdd(&mws[b * NFEAT * CIN + idx], s);
    }
}

// K2a: per (b,f): H_re/H_im from M, then G = H @ kernel (complex)
__global__ __launch_bounds__(64) void k2a_HG(const float* __restrict__ mws,
                                             const float* __restrict__ modes,
                                             const float* __restrict__ kre,
                                             const float* __restrict__ kim,
                                             float* __restrict__ gws) {
    const int bf = blockIdx.x;             // 128 = BATCH*NF
    const int b = bf >> 6, f = bf & 63;
    const int t = threadIdx.x;
    const int half = t >> 5;               // 0: re, 1: im
    const int lane = t & 31;

    const float u0 = TWO_PI_F * modes[f * 3 + 0];
    const float u1 = TWO_PI_F * modes[f * 3 + 1];
    const float u2 = TWO_PI_F * modes[f * 3 + 2];

    __shared__ float sH[2][32];

    const float* Mb = mws + b * NFEAT * CIN;
    float hv = 0.f;
#pragma unroll
    for (int fi = 0; fi < NFEAT; ++fi) {
        const int e0 = d_EX0[fi], e1 = d_EX1[fi], e2 = d_EX2[fi];
        const int deg = e0 + e1 + e2;
        float up = d_MULT[fi];
#pragma unroll
        for (int r = 0; r < 3; ++r) { if (r < e0) up *= u0; }
#pragma unroll
        for (int r = 0; r < 3; ++r) { if (r < e1) up *= u1; }
#pragma unroll
        for (int r = 0; r < 3; ++r) { if (r < e2) up *= u2; }
        float cc = (deg == 0) ? 1.f : ((deg == 2) ? -0.5f * up : 0.f);
        float cs = (deg == 1) ? up : ((deg == 3) ? -(1.f / 6.f) * up : 0.f);
        float coef = (half == 0) ? cc : -cs;
        hv = fmaf(coef, Mb[fi * CIN + lane], hv);
    }
    sH[half][lane] = hv;
    __syncthreads();

    float go = 0.f;
#pragma unroll 8
    for (int i2 = 0; i2 < CIN; ++i2) {
        float a = kre[((size_t)f * CIN + i2) * COUT + lane];
        float c = kim[((size_t)f * CIN + i2) * COUT + lane];
        float hre = sH[0][i2], him = sH[1][i2];
        go += (half == 0) ? (hre * a - him * c) : (hre * c + him * a);
    }
    gws[(((size_t)b * NF + f) * 2 + half) * COUT + lane] = go;
}

// K2b: V[b][feat][o] = sum_f ccos*Gre - csin*Gim ; fold in fc_w/fc_b
__global__ __launch_bounds__(640) void k2b_V(const float* __restrict__ gws,
                                             const float* __restrict__ modes,
                                             const float* __restrict__ fcw,
                                             const float* __restrict__ fcb,
                                             float* __restrict__ vws) {
    const int b = blockIdx.x;              // 2
    const int t = threadIdx.x;             // 640 = 20*32
    const int fi = t >> 5;
    const int o = t & 31;

    const int e0 = d_EX0[fi], e1 = d_EX1[fi], e2 = d_EX2[fi];
    const int deg = e0 + e1 + e2;
    const float mult = d_MULT[fi];

    float acc = 0.f;
    for (int f = 0; f < NF; ++f) {
        float u0 = TWO_PI_F * modes[f * 3 + 0];
        float u1 = TWO_PI_F * modes[f * 3 + 1];
        float u2 = TWO_PI_F * modes[f * 3 + 2];
        float up = mult;
        for (int r = 0; r < e0; ++r) up *= u0;
        for (int r = 0; r < e1; ++r) up *= u1;
        for (int r = 0; r < e2; ++r) up *= u2;
        float cc = (deg == 0) ? 1.f : ((deg == 2) ? -0.5f * up : 0.f);
        float cs = (deg == 1) ? up : ((deg == 3) ? -(1.f / 6.f) * up : 0.f);
        float gre = gws[(((size_t)b * NF + f) * 2 + 0) * COUT + o];
        float gim = gws[(((size_t)b * NF + f) * 2 + 1) * COUT + o];
        acc += cc * gre - cs * gim;
    }
    if (fi == 0) acc += fcb[o];
    else if (deg == 1) acc += fcw[(fi - 1) * COUT + o];
    vws[(b * NFEAT + fi) * COUT + o] = acc;
}

// K3: out[p][o] = gelu( sum_feat mono(x_p) * V[b][feat][o] )
// 8 threads per point, each owns a 4-channel quad (float4 stores).
__global__ __launch_bounds__(256) void k3_out(const float* __restrict__ x,
                                              const float* __restrict__ vws,
                                              float* __restrict__ out) {
    const int blk = blockIdx.x;            // 1024: 512 per batch
    const int b = blk >> 9;
    const int blkin = blk & 511;
    const int t = threadIdx.x;
    const int q = t & 7;
    const int o4 = q << 2;
    const int psub = t >> 3;               // 0..31
    const int PPB = NPTS / 512;
    const int NIT = PPB / 32;              // 16

    float4 v[NFEAT];
#pragma unroll
    for (int f = 0; f < NFEAT; ++f)
        v[f] = *reinterpret_cast<const float4*>(&vws[(b * NFEAT + f) * COUT + o4]);

    const size_t pbase = (size_t)b * NPTS + (size_t)blkin * PPB;

#pragma unroll 2
    for (int k = 0; k < NIT; ++k) {
        size_t p = pbase + (size_t)psub + 32u * (size_t)k;
        float x0 = x[p * 3 + 0];
        float x1 = x[p * 3 + 1];
        float x2 = x[p * 3 + 2];
        float m[NFEAT];
        monomials(x0, x1, x2, m);
        float4 y = make_float4(0.f, 0.f, 0.f, 0.f);
#pragma unroll
        for (int f = 0; f < NFEAT; ++f) {
            y.x = fmaf(m[f], v[f].x, y.x);
            y.y = fmaf(m[f], v[f].y, y.y);
            y.z = fmaf(m[f], v[f].z, y.z);
            y.w = fmaf(m[f], v[f].w, y.w);
        }
        y.x = gelu_f(y.x); y.y = gelu_f(y.y); y.z = gelu_f(y.z); y.w = gelu_f(y.w);
        *reinterpret_cast<float4*>(&out[p * 32 + o4]) = y;
    }
}

extern "C" void kernel_launch(void* const* d_in, const int* in_sizes, int n_in,
                              void* d_out, int out_size, void* d_ws, size_t ws_size,
                              hipStream_t stream) {
    const float* h     = (const float*)d_in[0];
    const float* x     = (const float*)d_in[1];
    const float* modes = (const float*)d_in[2];
    const float* kre   = (const float*)d_in[3];
    const float* kim   = (const float*)d_in[4];
    const float* fcw   = (const float*)d_in[5];
    const float* fcb   = (const float*)d_in[6];
    float* out = (float*)d_out;
    float* ws  = (float*)d_ws;

    hipMemsetAsync(ws + WS_M, 0, BATCH * NFEAT * CIN * sizeof(float), stream);

    k1_moments<<<1024, 256, 0, stream>>>(h, x, ws + WS_M);
    k2a_HG<<<BATCH * NF, 64, 0, stream>>>(ws + WS_M, modes, kre, kim, ws + WS_G);
    k2b_V<<<BATCH, NFEAT * COUT, 0, stream>>>(ws + WS_G, modes, fcw, fcb, ws + WS_V);
    k3_out<<<1024, 256, 0, stream>>>(x, ws + WS_V, out);
}